// Round 17
// baseline (115.877 us; speedup 1.0000x reference)
//
#include <hip/hip_runtime.h>
#include <stdint.h>

#define AS1 __attribute__((address_space(1)))
#define AS3 __attribute__((address_space(3)))

typedef __attribute__((ext_vector_type(8))) __bf16 bf16x8;
typedef __attribute__((ext_vector_type(4))) float f32x4;
typedef __attribute__((ext_vector_type(4))) unsigned int u32x4;
typedef __attribute__((ext_vector_type(2))) unsigned int u32x2;

static __device__ __forceinline__ void gload16(const void* g, void* l) {
    // async global->LDS, 16B per lane; LDS dest must be linear (base + lane*16)
    __builtin_amdgcn_global_load_lds((AS1 void*)(uintptr_t)g, (AS3 void*)l, 16, 0, 0);
}

static __device__ __forceinline__ unsigned cvt_pk_bf16(float lo, float hi) {
    unsigned r;
    asm volatile("v_cvt_pk_bf16_f32 %0, %1, %2" : "=v"(r) : "v"(lo), "v"(hi));
    return r;
}
static __device__ __forceinline__ unsigned short f2bf(float f) {
    return (unsigned short)(cvt_pk_bf16(f, 0.f) & 0xffffu);
}

static __device__ __forceinline__ f32x4 mfma16(bf16x8 a, bf16x8 b, f32x4 c) {
    return __builtin_amdgcn_mfma_f32_16x16x32_bf16(a, b, c, 0, 0, 0);
}

// raw v_exp_f32 (exp2); __builtin_exp2f w/o fast-math expands denormal guards
static __device__ __forceinline__ float fexp2(float x) {
    return __builtin_amdgcn_exp2f(x);
}

// ---------------------------------------------------------------------------
// Prep kernel: merged weight-transpose (4x) + activation convert (3x).
// Flat grid 7168 x 256 (see r15 comments). Both roles memory-bound.
// ---------------------------------------------------------------------------
__global__ __launch_bounds__(256) void k_prep(
    const float* __restrict__ w0, const float* __restrict__ w1,
    const float* __restrict__ w2, const float* __restrict__ w3,
    const float* __restrict__ aq, const float* __restrict__ ak,
    const float* __restrict__ av,
    unsigned short* __restrict__ o0, unsigned short* __restrict__ o1,
    unsigned short* __restrict__ o2, unsigned short* __restrict__ o3,
    unsigned short* __restrict__ cq, unsigned short* __restrict__ ck,
    unsigned short* __restrict__ cv) {
    __shared__ unsigned short tile[64][72];   // [n][k], padded (wtrans only)
    const int tid = threadIdx.x;
    const int bid = blockIdx.x;
    if (bid < 1024) {
        const float* W;
        unsigned short* Wt;
        switch (bid >> 8) {
            case 0: W = w0; Wt = o0; break;
            case 1: W = w1; Wt = o1; break;
            case 2: W = w2; Wt = o2; break;
            default: W = w3; Wt = o3; break;
        }
        const int xy = bid & 255;
        const int k0 = (xy & 15) * 64, n0 = (xy >> 4) * 64;
#pragma unroll
        for (int j = 0; j < 4; ++j) {
            int c = j * 256 + tid;            // 1024 float4 chunks
            int kr = c >> 4, c4 = c & 15;
            f32x4 v = *(const f32x4*)(W + (size_t)(k0 + kr) * 1024 + n0 + c4 * 4);
#pragma unroll
            for (int e = 0; e < 4; ++e) tile[c4 * 4 + e][kr] = f2bf(v[e]);
        }
        __syncthreads();
#pragma unroll
        for (int j = 0; j < 2; ++j) {
            int c = j * 256 + tid;            // 512 chunks of 8 bf16
            int nr = c >> 3, kc = c & 7;
            union { unsigned short s[8]; u32x4 v; } t;
#pragma unroll
            for (int e = 0; e < 8; ++e) t.s[e] = tile[nr][kc * 8 + e];
            *(u32x4*)(Wt + (size_t)(n0 + nr) * 1024 + k0 + kc * 8) = t.v;
        }
    } else {
        const int c = bid - 1024;
        const float* src; unsigned short* dst;
        switch (c >> 11) {
            case 0: src = aq; dst = cq; break;
            case 1: src = ak; dst = ck; break;
            default: src = av; dst = cv; break;
        }
        const size_t i = ((size_t)(c & 2047) * 256 + tid) * 8;
        f32x4 a = *(const f32x4*)(src + i);
        f32x4 b = *(const f32x4*)(src + i + 4);
        u32x4 o;
        o[0] = cvt_pk_bf16(a[0], a[1]);
        o[1] = cvt_pk_bf16(a[2], a[3]);
        o[2] = cvt_pk_bf16(b[0], b[1]);
        o[3] = cvt_pk_bf16(b[2], b[3]);
        *(u32x4*)(dst + i) = o;
    }
}

// ---------------------------------------------------------------------------
// GEMM body (r11-proven): C[M][N] = (A bf16 * Bt^T + bias) * cscale.
// Tile 64x128, BK=64, 4 waves (2x2), each 32x64. Double-buffered LDS,
// single barrier per K-step: STAGE(next) issued BEFORE compute(cur).
// ---------------------------------------------------------------------------
template <int OUT_F32>
static __device__ __forceinline__ void gemm_body(const unsigned short* __restrict__ A,
                                                 const unsigned short* __restrict__ Bt,
                                                 const float* __restrict__ bias,
                                                 void* __restrict__ Cp,
                                                 int M, int N, int K, float cscale,
                                                 char* smem) {
    constexpr int ASZ = 8192;
    char* sA = smem;                 // dbuf: [2][ASZ]
    char* sB = smem + 2 * ASZ;       // dbuf: [2][16384]
    const int tid = threadIdx.x;
    const int wave = tid >> 6, lane = tid & 63, g = lane >> 4, l16 = lane & 15;
    const int wm = wave & 1, wn = wave >> 1;
    const int m0 = blockIdx.x * 64, n0 = blockIdx.y * 128;

    f32x4 acc[2][4];
#pragma unroll
    for (int i = 0; i < 2; ++i)
#pragma unroll
        for (int j = 0; j < 4; ++j) acc[i][j] = (f32x4){0.f, 0.f, 0.f, 0.f};

    auto STAGE = [&](int k0, int buf) {
        char* dstA = sA + buf * ASZ;
#pragma unroll
        for (int j = 0; j < 2; ++j) {
            int c = j * 256 + tid;
            int row = c >> 3, w = c & 7, kc = w ^ (row & 7);
            gload16(A + (size_t)(m0 + row) * K + k0 + kc * 8, dstA + c * 16);
        }
        char* dstB = sB + buf * 16384;
#pragma unroll
        for (int j = 0; j < 4; ++j) {
            int c = j * 256 + tid;
            int row = c >> 3, w = c & 7, kc = w ^ (row & 7);
            gload16(Bt + (size_t)(n0 + row) * K + k0 + kc * 8, dstB + c * 16);
        }
    };

    const int nkt = K >> 6;
    STAGE(0, 0);
    __syncthreads();
    int cur = 0;
#pragma unroll 1
    for (int kt = 0; kt < nkt; ++kt) {
        if (kt + 1 < nkt) STAGE((kt + 1) << 6, cur ^ 1);
        const char* sAc = sA + cur * ASZ;
        const char* sBc = sB + cur * 16384;
#pragma unroll
        for (int ks = 0; ks < 2; ++ks) {
            bf16x8 af[2];
#pragma unroll
            for (int mi = 0; mi < 2; ++mi) {
                int row = wm * 32 + mi * 16 + l16;
                int c = (ks * 4 + g) ^ (row & 7);
                af[mi] = *(const bf16x8*)(sAc + row * 128 + c * 16);
            }
#pragma unroll
            for (int ni = 0; ni < 4; ++ni) {
                int row = wn * 64 + ni * 16 + l16;
                int c = (ks * 4 + g) ^ (row & 7);
                bf16x8 bfr = *(const bf16x8*)(sBc + row * 128 + c * 16);
#pragma unroll
                for (int mi = 0; mi < 2; ++mi)
                    acc[mi][ni] = mfma16(af[mi], bfr, acc[mi][ni]);
            }
        }
        __syncthreads();
        cur ^= 1;
    }
    // epilogue: bias + scale + store. C/D layout: col = lane&15, row = g*4 + r
#pragma unroll
    for (int ni = 0; ni < 4; ++ni) {
        int col = n0 + wn * 64 + ni * 16 + l16;
        float bn = bias[col];
#pragma unroll
        for (int mi = 0; mi < 2; ++mi) {
            int rbase = m0 + wm * 32 + mi * 16 + g * 4;
#pragma unroll
            for (int r = 0; r < 4; ++r) {
                float v = (acc[mi][ni][r] + bn) * cscale;
                if constexpr (OUT_F32)
                    ((float*)Cp)[(size_t)(rbase + r) * N + col] = v;
                else
                    ((unsigned short*)Cp)[(size_t)(rbase + r) * N + col] = f2bf(v);
            }
        }
    }
}

// QKV projections (bf16 A after prep); blockIdx.z selects the problem.
__global__ __launch_bounds__(256) void k_gemm_qkv(
    const unsigned short* __restrict__ Aq, const unsigned short* __restrict__ Ak,
    const unsigned short* __restrict__ Av,
    const unsigned short* __restrict__ Wq, const unsigned short* __restrict__ Wk,
    const unsigned short* __restrict__ Wv,
    const float* __restrict__ bq, const float* __restrict__ bk, const float* __restrict__ bv,
    unsigned short* __restrict__ Q2, unsigned short* __restrict__ K2,
    unsigned short* __restrict__ V2) {
    extern __shared__ __align__(16) char smem[];
    const unsigned short* A; const unsigned short* Bt; const float* bias;
    unsigned short* C; float sc;
    switch (blockIdx.z) {
        // exp2-domain scale 0.125*log2(e) folded into Q projection
        case 0:  A = Aq; Bt = Wq; bias = bq; C = Q2; sc = 0.18033688011112042f; break;
        case 1:  A = Ak; Bt = Wk; bias = bk; C = K2; sc = 1.0f; break;
        default: A = Av; Bt = Wv; bias = bv; C = V2; sc = 1.0f; break;
    }
    gemm_body<0>(A, Bt, bias, C, 4096, 1024, 1024, sc, smem);
}

// Output projection (bf16 A, f32 out)
__global__ __launch_bounds__(256) void k_gemm_o(const unsigned short* __restrict__ ctx,
                                                const unsigned short* __restrict__ Wo,
                                                const float* __restrict__ bo,
                                                float* __restrict__ out) {
    extern __shared__ __align__(16) char smem[];
    gemm_body<1>(ctx, Wo, bo, out, 4096, 1024, 1024, 1.0f, smem);
}

// ---------------------------------------------------------------------------
// Per-head V transpose: V2[(b*2048+s)][1024] bf16 -> Vt[(bh*64+d)][2048] bf16
// ---------------------------------------------------------------------------
__global__ __launch_bounds__(256) void k_vtrans(const unsigned short* __restrict__ V2,
                                                unsigned short* __restrict__ Vt) {
    __shared__ unsigned short tile[64][72];   // [d][s]
    const int tid = threadIdx.x;
    const int s0 = blockIdx.x * 64;
    const int bh = blockIdx.y, b = bh >> 4, h = bh & 15;
#pragma unroll
    for (int j = 0; j < 2; ++j) {
        int c = j * 256 + tid;
        int sr = c >> 3, dc = c & 7;
        union { u32x4 v; unsigned short s[8]; } t;
        t.v = *(const u32x4*)(V2 + (size_t)(b * 2048 + s0 + sr) * 1024 + h * 64 + dc * 8);
#pragma unroll
        for (int e = 0; e < 8; ++e) tile[dc * 8 + e][sr] = t.s[e];
    }
    __syncthreads();
#pragma unroll
    for (int j = 0; j < 2; ++j) {
        int c = j * 256 + tid;
        int dr = c >> 3, sc = c & 7;
        union { unsigned short s[8]; u32x4 v; } t;
#pragma unroll
        for (int e = 0; e < 8; ++e) t.s[e] = tile[dr][sc * 8 + e];
        *(u32x4*)(Vt + ((size_t)bh * 64 + dr) * 2048 + s0 + sc * 8) = t.v;
    }
}

// ---------------------------------------------------------------------------
// Causal flash attention — r11 structure with K double-buffered and ONE
// barrier per kv-step (round 17). Delta vs r11 (proven 47.9 us): sK[2]
// (LDS 28->36KB, same 4 blocks/CU), bar1 removed; STAGE(next) issued before
// compute so loads land under the full QK+softmax+PV phase (GEMM-proven
// schedule). Per-wave P write->read needs no barrier (same-wave lgkmcnt).
// ---------------------------------------------------------------------------
__global__ __launch_bounds__(128) void k_attn(const unsigned short* __restrict__ Q2,
                                              const unsigned short* __restrict__ K2,
                                              const unsigned short* __restrict__ Vt,
                                              unsigned short* __restrict__ ctx) {
    __shared__ __align__(16) char sK[2][8192];   // 64 kv x 64 d bf16, chunk-swizzled
    __shared__ __align__(16) char sV[2][8192];   // 64 d x 64 kv bf16, chunk-swizzled
    __shared__ __align__(16) char sP[2][2048];   // per-wave P^T: 16 q x 64 kv bf16

    const int tid = threadIdx.x, w = tid >> 6, lane = tid & 63;
    const int g = lane >> 4, l16 = lane & 15;
    const int bid = blockIdx.x;
    const int xcd = bid & 7, j = bid >> 3;       // 128 blocks per XCD
    const int bh = xcd * 4 + (j & 3);            // 4 heads per XCD
    const int p = j >> 2;                        // pair index 0..31
    const int b = bh >> 4, h = bh & 15;
    const int swzl = (l16 & 7) << 4;

    // staging source addresses (rule 21: pre-swizzled source, linear LDS dest)
    const int r0 = tid >> 3;                     // 0..15
    const int sc0 = (tid & 7) ^ (r0 & 7);
    const unsigned short* ksrc = K2 + (size_t)(b * 2048 + r0) * 1024 + h * 64 + sc0 * 8;
    const unsigned short* vsrc = Vt + ((size_t)bh * 64 + r0) * 2048 + sc0 * 8;
    char* const myp = sP[w];
    char* const mypw = myp + l16 * 128;

#pragma unroll 1
    for (int t2 = 0; t2 < 2; ++t2) {
        const int t = t2 ? p : (63 - p);         // big tile first
        const int wq0 = t * 32 + w * 16;         // first q row of this wave
        const int qg = wq0 + l16;                // q owned by this lane

        const unsigned short* qp = Q2 + (size_t)(b * 2048 + wq0 + l16) * 1024 + h * 64;
        bf16x8 qf0 = *(const bf16x8*)(qp + g * 8);
        bf16x8 qf1 = *(const bf16x8*)(qp + 32 + g * 8);

        f32x4 accO[4];
#pragma unroll
        for (int i = 0; i < 4; ++i) accO[i] = (f32x4){0.f, 0.f, 0.f, 0.f};
        float m = 0.f, lsum = 0.f;               // frozen m; per-lane lsum partial

        const int nkv = (t >> 1) + 1;
        const int diag = t >> 1;
        // prologue: stage tile 0 into buf 0 (prev tile's reads done: last-step
        // barrier of the previous t2 iteration covers the hazard)
#pragma unroll
        for (int rr = 0; rr < 4; ++rr) {
            gload16(ksrc + (size_t)(rr * 16) * 1024, sK[0] + rr * 2048 + tid * 16);
            gload16(vsrc + (size_t)(rr * 16) * 2048, sV[0] + rr * 2048 + tid * 16);
        }
        __syncthreads();                         // drains vmcnt: K[0], V[0] ready

        // loop-carried staging pointers (advance by constant strides)
        const unsigned short* kstage = ksrc + 64 * 1024;
        const unsigned short* vstage = vsrc + 64;

#pragma unroll 1
        for (int kt = 0; kt < nkv; ++kt) {
            const int cur = kt & 1;
            const int kv0 = kt * 64;
            // ---- stage next K+V into buf[cur^1] (lands under compute) ----
            if (kt + 1 < nkv) {
#pragma unroll
                for (int rr = 0; rr < 4; ++rr) {
                    gload16(kstage + (size_t)(rr * 16) * 1024, sK[cur ^ 1] + rr * 2048 + tid * 16);
                    gload16(vstage + (size_t)(rr * 16) * 2048, sV[cur ^ 1] + rr * 2048 + tid * 16);
                }
                kstage += 64 * 1024;
                vstage += 64;
            }
            // ---- QK^T from sK[cur] ----
            float s[16];
            __builtin_amdgcn_s_setprio(1);
#pragma unroll
            for (int blk = 0; blk < 4; ++blk) {
                const int rl = blk * 16 + l16;
                const char* krow = sK[cur] + rl * 128;
                bf16x8 kf0 = *(const bf16x8*)(krow + ((g << 4) ^ swzl));
                bf16x8 kf1 = *(const bf16x8*)(krow + (((4 + g) << 4) ^ swzl));
                f32x4 a = (f32x4){0.f, 0.f, 0.f, 0.f};
                a = mfma16(kf0, qf0, a);
                a = mfma16(kf1, qf1, a);
#pragma unroll
                for (int rr = 0; rr < 4; ++rr) s[blk * 4 + rr] = a[rr];
            }
            __builtin_amdgcn_s_setprio(0);
            // ---- softmax (frozen-m fast path) ----
            if (kt == diag) {
#pragma unroll
                for (int j2 = 0; j2 < 16; ++j2) {
                    int kvg = kv0 + (j2 >> 2) * 16 + g * 4 + (j2 & 3);
                    if (kvg > qg) s[j2] = -1e9f;
                }
            }
            float ps0 = 0.f, ps1 = 0.f, ps2 = 0.f, ps3 = 0.f;
            unsigned pk[8];
#pragma unroll
            for (int j2 = 0; j2 < 4; ++j2) {
                float a0 = fexp2(s[4 * j2] - m);
                float a1 = fexp2(s[4 * j2 + 1] - m);
                float a2 = fexp2(s[4 * j2 + 2] - m);
                float a3 = fexp2(s[4 * j2 + 3] - m);
                ps0 += a0; ps1 += a1; ps2 += a2; ps3 += a3;
                pk[2 * j2] = cvt_pk_bf16(a0, a1);
                pk[2 * j2 + 1] = cvt_pk_bf16(a2, a3);
            }
            float ps = (ps0 + ps1) + (ps2 + ps3);
            if (__any(ps > 16777216.f)) {        // overflow trigger: true-max rescale
                float c1 = fmaxf(fmaxf(s[0], s[1]), s[2]);
                c1 = fmaxf(fmaxf(c1, s[3]), s[4]);
                c1 = fmaxf(fmaxf(c1, s[5]), s[6]);
                c1 = fmaxf(c1, s[7]);
                float c2 = fmaxf(fmaxf(s[8], s[9]), s[10]);
                c2 = fmaxf(fmaxf(c2, s[11]), s[12]);
                c2 = fmaxf(fmaxf(c2, s[13]), s[14]);
                c2 = fmaxf(c2, s[15]);
                float mx = fmaxf(c1, c2);
                mx = fmaxf(mx, __shfl_xor(mx, 16));
                mx = fmaxf(mx, __shfl_xor(mx, 32));
                float mnew = fmaxf(m, mx);
                float scl = fexp2(m - mnew);
                lsum *= scl;
#pragma unroll
                for (int dt = 0; dt < 4; ++dt) accO[dt] = accO[dt] * scl;
                m = mnew;                        // wave-uniform (all lanes branch)
                ps = 0.f;
#pragma unroll
                for (int j2 = 0; j2 < 8; ++j2) {
                    float p0 = fexp2(s[2 * j2] - m);
                    float p1 = fexp2(s[2 * j2 + 1] - m);
                    ps += p0 + p1;
                    pk[j2] = cvt_pk_bf16(p0, p1);
                }
            }
            lsum += ps;
            // write P^T (bf16) to per-wave swizzled LDS (same-wave read below:
            // ordered by lgkmcnt, no barrier needed)
#pragma unroll
            for (int blk = 0; blk < 4; ++blk) {
                u32x2 pw = {pk[blk * 2], pk[blk * 2 + 1]};
                *(u32x2*)(mypw + ((blk * 32 + g * 8) ^ swzl)) = pw;
            }
            // PV: O^T[d][q] += V^T * P^T from sV[cur]
            __builtin_amdgcn_s_setprio(1);
#pragma unroll
            for (int kvh = 0; kvh < 2; ++kvh) {
                bf16x8 pf = *(const bf16x8*)(mypw + ((kvh * 64 + g * 16) ^ swzl));
#pragma unroll
                for (int dt = 0; dt < 4; ++dt) {
                    const int rv = dt * 16 + l16;
                    bf16x8 vf = *(const bf16x8*)(sV[cur] + rv * 128 + (((kvh * 4 + g) << 4) ^ swzl));
                    accO[dt] = mfma16(vf, pf, accO[dt]);
                }
            }
            __builtin_amdgcn_s_setprio(0);
            __syncthreads();                     // ONE barrier/step: drains staging,
                                                 // all reads of buf[cur] complete
        }
        // final per-q-row reduce of lsum partials across the 4 kv-groups
        float v = lsum;
        v += __shfl_xor(v, 16);
        v += __shfl_xor(v, 32);
        float inv = 1.f / v;
        // O^T: lane owns col q=l16; row d = dt*16 + g*4 + r -> ctx bf16 [4096][1024]
        unsigned short* cp = ctx + (size_t)(b * 2048 + wq0 + l16) * 1024 + h * 64 + g * 4;
#pragma unroll
        for (int dt = 0; dt < 4; ++dt) {
            u32x2 o;
            o[0] = cvt_pk_bf16(accO[dt][0] * inv, accO[dt][1] * inv);
            o[1] = cvt_pk_bf16(accO[dt][2] * inv, accO[dt][3] * inv);
            *(u32x2*)(cp + dt * 16) = o;
        }
    }
}

// ---------------------------------------------------------------------------
extern "C" void kernel_launch(void* const* d_in, const int* in_sizes, int n_in,
                              void* d_out, int out_size, void* d_ws, size_t ws_size,
                              hipStream_t stream) {
    const float* query = (const float*)d_in[0];
    const float* key   = (const float*)d_in[1];
    const float* value = (const float*)d_in[2];
    // d_in[3] = mask: fixed causal tril, applied analytically
    const float* wq = (const float*)d_in[4];
    const float* bq = (const float*)d_in[5];
    const float* wk = (const float*)d_in[6];
    const float* bk = (const float*)d_in[7];
    const float* wv = (const float*)d_in[8];
    const float* bv = (const float*)d_in[9];
    const float* wo = (const float*)d_in[10];
    const float* bo = (const float*)d_in[11];
    float* out = (float*)d_out;

    char* ws = (char*)d_ws;
    unsigned short* Wtq = (unsigned short*)ws;                 // 4 x 2MB: 0..8MB
    unsigned short* Wtk = Wtq + 1024 * 1024;
    unsigned short* Wtv = Wtk + 1024 * 1024;
    unsigned short* Wto = Wtv + 1024 * 1024;
    unsigned short* Q2  = Wto + 1024 * 1024;                   // 8..16MB
    unsigned short* K2  = Q2 + 4096 * 1024;                    // 16..24MB
    unsigned short* V2  = K2 + 4096 * 1024;                    // 24..32MB
    unsigned short* Aq  = V2 + 4096 * 1024;                    // 32..40MB (bf16 activations)
    unsigned short* Ak  = Aq + 4096 * 1024;                    // 40..48MB
    unsigned short* Av  = Ak + 4096 * 1024;                    // 48..56MB
    // Aq/Ak dead after k_gemm_qkv -> reuse for Vt and ctx:
    unsigned short* Vt  = Aq;                                  // 32..40MB
    unsigned short* ctx = Ak;                                  // 40..48MB

    dim3 blk(256);
    k_prep<<<dim3(7168), blk, 0, stream>>>(wq, wk, wv, wo, query, key, value,
                                           Wtq, Wtk, Wtv, Wto, Aq, Ak, Av);

    k_gemm_qkv<<<dim3(64, 8, 3), blk, 49152, stream>>>(Aq, Ak, Av,
                                                       Wtq, Wtk, Wtv, bq, bk, bv,
                                                       Q2, K2, V2);

    k_vtrans<<<dim3(32, 32), blk, 0, stream>>>(V2, Vt);
    k_attn<<<dim3(1024), dim3(128), 0, stream>>>(Q2, K2, Vt, ctx);

    k_gemm_o<<<dim3(64, 8), blk, 49152, stream>>>(ctx, Wto, bo, out);
}

// Round 18
// 109.743 us; speedup vs baseline: 1.0559x; 1.0559x over previous
//
#include <hip/hip_runtime.h>
#include <stdint.h>

#define AS1 __attribute__((address_space(1)))
#define AS3 __attribute__((address_space(3)))

typedef __attribute__((ext_vector_type(8))) __bf16 bf16x8;
typedef __attribute__((ext_vector_type(4))) float f32x4;
typedef __attribute__((ext_vector_type(4))) unsigned int u32x4;
typedef __attribute__((ext_vector_type(2))) unsigned int u32x2;

static __device__ __forceinline__ void gload16(const void* g, void* l) {
    // async global->LDS, 16B per lane; LDS dest must be linear (base + lane*16)
    __builtin_amdgcn_global_load_lds((AS1 void*)(uintptr_t)g, (AS3 void*)l, 16, 0, 0);
}

static __device__ __forceinline__ unsigned cvt_pk_bf16(float lo, float hi) {
    unsigned r;
    asm volatile("v_cvt_pk_bf16_f32 %0, %1, %2" : "=v"(r) : "v"(lo), "v"(hi));
    return r;
}
static __device__ __forceinline__ unsigned short f2bf(float f) {
    return (unsigned short)(cvt_pk_bf16(f, 0.f) & 0xffffu);
}

static __device__ __forceinline__ f32x4 mfma16(bf16x8 a, bf16x8 b, f32x4 c) {
    return __builtin_amdgcn_mfma_f32_16x16x32_bf16(a, b, c, 0, 0, 0);
}

// raw v_exp_f32 (exp2); __builtin_exp2f w/o fast-math expands denormal guards
static __device__ __forceinline__ float fexp2(float x) {
    return __builtin_amdgcn_exp2f(x);
}

// ---------------------------------------------------------------------------
// Prep kernel: merged weight-transpose (4x) + activation convert (3x).
// Flat grid 7168 x 256 (see r15 comments). Both roles memory-bound.
// ---------------------------------------------------------------------------
__global__ __launch_bounds__(256) void k_prep(
    const float* __restrict__ w0, const float* __restrict__ w1,
    const float* __restrict__ w2, const float* __restrict__ w3,
    const float* __restrict__ aq, const float* __restrict__ ak,
    const float* __restrict__ av,
    unsigned short* __restrict__ o0, unsigned short* __restrict__ o1,
    unsigned short* __restrict__ o2, unsigned short* __restrict__ o3,
    unsigned short* __restrict__ cq, unsigned short* __restrict__ ck,
    unsigned short* __restrict__ cv) {
    __shared__ unsigned short tile[64][72];   // [n][k], padded (wtrans only)
    const int tid = threadIdx.x;
    const int bid = blockIdx.x;
    if (bid < 1024) {
        const float* W;
        unsigned short* Wt;
        switch (bid >> 8) {
            case 0: W = w0; Wt = o0; break;
            case 1: W = w1; Wt = o1; break;
            case 2: W = w2; Wt = o2; break;
            default: W = w3; Wt = o3; break;
        }
        const int xy = bid & 255;
        const int k0 = (xy & 15) * 64, n0 = (xy >> 4) * 64;
#pragma unroll
        for (int j = 0; j < 4; ++j) {
            int c = j * 256 + tid;            // 1024 float4 chunks
            int kr = c >> 4, c4 = c & 15;
            f32x4 v = *(const f32x4*)(W + (size_t)(k0 + kr) * 1024 + n0 + c4 * 4);
#pragma unroll
            for (int e = 0; e < 4; ++e) tile[c4 * 4 + e][kr] = f2bf(v[e]);
        }
        __syncthreads();
#pragma unroll
        for (int j = 0; j < 2; ++j) {
            int c = j * 256 + tid;            // 512 chunks of 8 bf16
            int nr = c >> 3, kc = c & 7;
            union { unsigned short s[8]; u32x4 v; } t;
#pragma unroll
            for (int e = 0; e < 8; ++e) t.s[e] = tile[nr][kc * 8 + e];
            *(u32x4*)(Wt + (size_t)(n0 + nr) * 1024 + k0 + kc * 8) = t.v;
        }
    } else {
        const int c = bid - 1024;
        const float* src; unsigned short* dst;
        switch (c >> 11) {
            case 0: src = aq; dst = cq; break;
            case 1: src = ak; dst = ck; break;
            default: src = av; dst = cv; break;
        }
        const size_t i = ((size_t)(c & 2047) * 256 + tid) * 8;
        f32x4 a = *(const f32x4*)(src + i);
        f32x4 b = *(const f32x4*)(src + i + 4);
        u32x4 o;
        o[0] = cvt_pk_bf16(a[0], a[1]);
        o[1] = cvt_pk_bf16(a[2], a[3]);
        o[2] = cvt_pk_bf16(b[0], b[1]);
        o[3] = cvt_pk_bf16(b[2], b[3]);
        *(u32x4*)(dst + i) = o;
    }
}

// ---------------------------------------------------------------------------
// GEMM body (r11-proven): C = (A bf16 * Bt^T + bias) * cscale.
// Tile 64x128, BK=64, 4 waves (2x2), each 32x64. Double-buffered LDS,
// single barrier per K-step: STAGE(next) issued BEFORE compute(cur).
// OUT_MODE: 0 = bf16 row-major [M][N]; 1 = f32 row-major;
//           2 = bf16 per-head V-transpose: Vt[(b*16+h)*64 + (n&63)][s]
//               (4 s-consecutive accs -> one contiguous 8B store).
// ---------------------------------------------------------------------------
template <int OUT_MODE>
static __device__ __forceinline__ void gemm_body(const unsigned short* __restrict__ A,
                                                 const unsigned short* __restrict__ Bt,
                                                 const float* __restrict__ bias,
                                                 void* __restrict__ Cp,
                                                 int M, int N, int K, float cscale,
                                                 char* smem) {
    constexpr int ASZ = 8192;
    char* sA = smem;                 // dbuf: [2][ASZ]
    char* sB = smem + 2 * ASZ;       // dbuf: [2][16384]
    const int tid = threadIdx.x;
    const int wave = tid >> 6, lane = tid & 63, g = lane >> 4, l16 = lane & 15;
    const int wm = wave & 1, wn = wave >> 1;
    const int m0 = blockIdx.x * 64, n0 = blockIdx.y * 128;

    f32x4 acc[2][4];
#pragma unroll
    for (int i = 0; i < 2; ++i)
#pragma unroll
        for (int j = 0; j < 4; ++j) acc[i][j] = (f32x4){0.f, 0.f, 0.f, 0.f};

    auto STAGE = [&](int k0, int buf) {
        char* dstA = sA + buf * ASZ;
#pragma unroll
        for (int j = 0; j < 2; ++j) {
            int c = j * 256 + tid;
            int row = c >> 3, w = c & 7, kc = w ^ (row & 7);
            gload16(A + (size_t)(m0 + row) * K + k0 + kc * 8, dstA + c * 16);
        }
        char* dstB = sB + buf * 16384;
#pragma unroll
        for (int j = 0; j < 4; ++j) {
            int c = j * 256 + tid;
            int row = c >> 3, w = c & 7, kc = w ^ (row & 7);
            gload16(Bt + (size_t)(n0 + row) * K + k0 + kc * 8, dstB + c * 16);
        }
    };

    const int nkt = K >> 6;
    STAGE(0, 0);
    __syncthreads();
    int cur = 0;
#pragma unroll 1
    for (int kt = 0; kt < nkt; ++kt) {
        if (kt + 1 < nkt) STAGE((kt + 1) << 6, cur ^ 1);
        const char* sAc = sA + cur * ASZ;
        const char* sBc = sB + cur * 16384;
#pragma unroll
        for (int ks = 0; ks < 2; ++ks) {
            bf16x8 af[2];
#pragma unroll
            for (int mi = 0; mi < 2; ++mi) {
                int row = wm * 32 + mi * 16 + l16;
                int c = (ks * 4 + g) ^ (row & 7);
                af[mi] = *(const bf16x8*)(sAc + row * 128 + c * 16);
            }
#pragma unroll
            for (int ni = 0; ni < 4; ++ni) {
                int row = wn * 64 + ni * 16 + l16;
                int c = (ks * 4 + g) ^ (row & 7);
                bf16x8 bfr = *(const bf16x8*)(sBc + row * 128 + c * 16);
#pragma unroll
                for (int mi = 0; mi < 2; ++mi)
                    acc[mi][ni] = mfma16(af[mi], bfr, acc[mi][ni]);
            }
        }
        __syncthreads();
        cur ^= 1;
    }
    // epilogue: bias + scale + store. C/D layout: col = lane&15, row = g*4 + r
#pragma unroll
    for (int ni = 0; ni < 4; ++ni) {
        int col = n0 + wn * 64 + ni * 16 + l16;
        float bn = bias[col];
#pragma unroll
        for (int mi = 0; mi < 2; ++mi) {
            int rbase = m0 + wm * 32 + mi * 16 + g * 4;
            if constexpr (OUT_MODE == 2) {
                // Vt[(b*16 + h)*64 + dl][s]; r=0..3 -> s-consecutive 8B
                const int h = col >> 6, dl = col & 63;
                const int bb = rbase >> 11, sl = rbase & 2047;
                u32x2 o;
                o[0] = cvt_pk_bf16((acc[mi][ni][0] + bn) * cscale,
                                   (acc[mi][ni][1] + bn) * cscale);
                o[1] = cvt_pk_bf16((acc[mi][ni][2] + bn) * cscale,
                                   (acc[mi][ni][3] + bn) * cscale);
                unsigned short* vt = (unsigned short*)Cp;
                *(u32x2*)(vt + ((size_t)(bb * 16 + h) * 64 + dl) * 2048 + sl) = o;
            } else {
#pragma unroll
                for (int r = 0; r < 4; ++r) {
                    float v = (acc[mi][ni][r] + bn) * cscale;
                    if constexpr (OUT_MODE == 1)
                        ((float*)Cp)[(size_t)(rbase + r) * N + col] = v;
                    else
                        ((unsigned short*)Cp)[(size_t)(rbase + r) * N + col] = f2bf(v);
                }
            }
        }
    }
}

// QKV projections (bf16 A after prep); blockIdx.z selects the problem.
// z=2 (V) writes the per-head-transposed Vt directly (OUT_MODE 2) -> no
// separate vtrans kernel.
__global__ __launch_bounds__(256) void k_gemm_qkv(
    const unsigned short* __restrict__ Aq, const unsigned short* __restrict__ Ak,
    const unsigned short* __restrict__ Av,
    const unsigned short* __restrict__ Wq, const unsigned short* __restrict__ Wk,
    const unsigned short* __restrict__ Wv,
    const float* __restrict__ bq, const float* __restrict__ bk, const float* __restrict__ bv,
    unsigned short* __restrict__ Q2, unsigned short* __restrict__ K2,
    unsigned short* __restrict__ Vt) {
    extern __shared__ __align__(16) char smem[];
    switch (blockIdx.z) {
        // exp2-domain scale 0.125*log2(e) folded into Q projection
        case 0:
            gemm_body<0>(Aq, Wq, bq, Q2, 4096, 1024, 1024, 0.18033688011112042f, smem);
            break;
        case 1:
            gemm_body<0>(Ak, Wk, bk, K2, 4096, 1024, 1024, 1.0f, smem);
            break;
        default:
            gemm_body<2>(Av, Wv, bv, Vt, 4096, 1024, 1024, 1.0f, smem);
            break;
    }
}

// Output projection (bf16 A, f32 out)
__global__ __launch_bounds__(256) void k_gemm_o(const unsigned short* __restrict__ ctx,
                                                const unsigned short* __restrict__ Wo,
                                                const float* __restrict__ bo,
                                                float* __restrict__ out) {
    extern __shared__ __align__(16) char smem[];
    gemm_body<1>(ctx, Wo, bo, out, 4096, 1024, 1024, 1.0f, smem);
}

// ---------------------------------------------------------------------------
// Causal flash attention — EXACT r11/r16 champion (proven 47.9 us).
// Grid 1024 x 128 thr (2 waves, 32-q tile). Uniform pairs {63-p, p} = 33
// kv-steps/block. K single-buffered, V dbuf, 2 barriers/step. Swapped QK^T
// (lane owns q=lane&15 -> softmax lane-local). Frozen-m softmax (m=0, exp2
// domain; 0.125*log2e folded into Q proj), overflow trigger -> true-max
// rescale. raw v_exp_f32; loop-carried staging pointers; 4-way ps sums.
// ---------------------------------------------------------------------------
__global__ __launch_bounds__(128) void k_attn(const unsigned short* __restrict__ Q2,
                                              const unsigned short* __restrict__ K2,
                                              const unsigned short* __restrict__ Vt,
                                              unsigned short* __restrict__ ctx) {
    __shared__ __align__(16) char sK[8192];      // 64 kv x 64 d bf16, chunk-swizzled
    __shared__ __align__(16) char sV[2][8192];   // 64 d x 64 kv bf16, chunk-swizzled
    __shared__ __align__(16) char sP[2][2048];   // per-wave P^T: 16 q x 64 kv bf16

    const int tid = threadIdx.x, w = tid >> 6, lane = tid & 63;
    const int g = lane >> 4, l16 = lane & 15;
    const int bid = blockIdx.x;
    const int xcd = bid & 7, j = bid >> 3;       // 128 blocks per XCD
    const int bh = xcd * 4 + (j & 3);            // 4 heads per XCD
    const int p = j >> 2;                        // pair index 0..31
    const int b = bh >> 4, h = bh & 15;
    const int swzl = (l16 & 7) << 4;

    // staging source addresses (rule 21: pre-swizzled source, linear LDS dest)
    const int r0 = tid >> 3;                     // 0..15
    const int sc0 = (tid & 7) ^ (r0 & 7);
    const unsigned short* ksrc = K2 + (size_t)(b * 2048 + r0) * 1024 + h * 64 + sc0 * 8;
    const unsigned short* vsrc = Vt + ((size_t)bh * 64 + r0) * 2048 + sc0 * 8;
    char* const myp = sP[w];
    char* const mypw = myp + l16 * 128;

#pragma unroll 1
    for (int t2 = 0; t2 < 2; ++t2) {
        const int t = t2 ? p : (63 - p);         // big tile first
        const int wq0 = t * 32 + w * 16;         // first q row of this wave
        const int qg = wq0 + l16;                // q owned by this lane

        const unsigned short* qp = Q2 + (size_t)(b * 2048 + wq0 + l16) * 1024 + h * 64;
        bf16x8 qf0 = *(const bf16x8*)(qp + g * 8);
        bf16x8 qf1 = *(const bf16x8*)(qp + 32 + g * 8);

        f32x4 accO[4];
#pragma unroll
        for (int i = 0; i < 4; ++i) accO[i] = (f32x4){0.f, 0.f, 0.f, 0.f};
        float m = 0.f, lsum = 0.f;               // frozen m; per-lane lsum partial

        const int nkv = (t >> 1) + 1;
        const int diag = t >> 1;
        __syncthreads();                         // prev tile's reads done
#pragma unroll
        for (int rr = 0; rr < 4; ++rr) {
            gload16(ksrc + (size_t)(rr * 16) * 1024, sK + rr * 2048 + tid * 16);
            gload16(vsrc + (size_t)(rr * 16) * 2048, sV[0] + rr * 2048 + tid * 16);
        }
        __syncthreads();                         // drains vmcnt: K, V[0] ready

        // loop-carried staging pointers (advance by constant strides)
        const unsigned short* kstage = ksrc + 64 * 1024;
        const unsigned short* vstage = vsrc + 64;

#pragma unroll 1
        for (int kt = 0; kt < nkv; ++kt) {
            const int cur = kt & 1;
            const int kv0 = kt * 64;
            // ---- phase 1: QK^T from sK (single buffer) ----
            float s[16];
            __builtin_amdgcn_s_setprio(1);
#pragma unroll
            for (int blk = 0; blk < 4; ++blk) {
                const int rl = blk * 16 + l16;
                const char* krow = sK + rl * 128;
                bf16x8 kf0 = *(const bf16x8*)(krow + ((g << 4) ^ swzl));
                bf16x8 kf1 = *(const bf16x8*)(krow + (((4 + g) << 4) ^ swzl));
                f32x4 a = (f32x4){0.f, 0.f, 0.f, 0.f};
                a = mfma16(kf0, qf0, a);
                a = mfma16(kf1, qf1, a);
#pragma unroll
                for (int rr = 0; rr < 4; ++rr) s[blk * 4 + rr] = a[rr];
            }
            __builtin_amdgcn_s_setprio(0);
            __syncthreads();                     // bar1: all waves done with sK
            // ---- stage next K (same buffer) + next V (other buffer) ----
            if (kt + 1 < nkv) {
#pragma unroll
                for (int rr = 0; rr < 4; ++rr) {
                    gload16(kstage + (size_t)(rr * 16) * 1024, sK + rr * 2048 + tid * 16);
                    gload16(vstage + (size_t)(rr * 16) * 2048, sV[cur ^ 1] + rr * 2048 + tid * 16);
                }
                kstage += 64 * 1024;
                vstage += 64;
            }
            // ---- phase 2: softmax (frozen-m fast path) + PV from sV[cur] ----
            if (kt == diag) {
#pragma unroll
                for (int j2 = 0; j2 < 16; ++j2) {
                    int kvg = kv0 + (j2 >> 2) * 16 + g * 4 + (j2 & 3);
                    if (kvg > qg) s[j2] = -1e9f;
                }
            }
            float ps0 = 0.f, ps1 = 0.f, ps2 = 0.f, ps3 = 0.f;
            unsigned pk[8];
#pragma unroll
            for (int j2 = 0; j2 < 4; ++j2) {
                float a0 = fexp2(s[4 * j2] - m);
                float a1 = fexp2(s[4 * j2 + 1] - m);
                float a2 = fexp2(s[4 * j2 + 2] - m);
                float a3 = fexp2(s[4 * j2 + 3] - m);
                ps0 += a0; ps1 += a1; ps2 += a2; ps3 += a3;
                pk[2 * j2] = cvt_pk_bf16(a0, a1);
                pk[2 * j2 + 1] = cvt_pk_bf16(a2, a3);
            }
            float ps = (ps0 + ps1) + (ps2 + ps3);
            if (__any(ps > 16777216.f)) {        // overflow trigger: true-max rescale
                float c1 = fmaxf(fmaxf(s[0], s[1]), s[2]);
                c1 = fmaxf(fmaxf(c1, s[3]), s[4]);
                c1 = fmaxf(fmaxf(c1, s[5]), s[6]);
                c1 = fmaxf(c1, s[7]);
                float c2 = fmaxf(fmaxf(s[8], s[9]), s[10]);
                c2 = fmaxf(fmaxf(c2, s[11]), s[12]);
                c2 = fmaxf(fmaxf(c2, s[13]), s[14]);
                c2 = fmaxf(c2, s[15]);
                float mx = fmaxf(c1, c2);
                mx = fmaxf(mx, __shfl_xor(mx, 16));
                mx = fmaxf(mx, __shfl_xor(mx, 32));
                float mnew = fmaxf(m, mx);
                float scl = fexp2(m - mnew);
                lsum *= scl;
#pragma unroll
                for (int dt = 0; dt < 4; ++dt) accO[dt] = accO[dt] * scl;
                m = mnew;                        // wave-uniform (all lanes branch)
                ps = 0.f;
#pragma unroll
                for (int j2 = 0; j2 < 8; ++j2) {
                    float p0 = fexp2(s[2 * j2] - m);
                    float p1 = fexp2(s[2 * j2 + 1] - m);
                    ps += p0 + p1;
                    pk[j2] = cvt_pk_bf16(p0, p1);
                }
            }
            lsum += ps;
            // write P^T (bf16) to per-wave swizzled LDS
#pragma unroll
            for (int blk = 0; blk < 4; ++blk) {
                u32x2 pw = {pk[blk * 2], pk[blk * 2 + 1]};
                *(u32x2*)(mypw + ((blk * 32 + g * 8) ^ swzl)) = pw;
            }
            // PV: O^T[d][q] += V^T * P^T
            __builtin_amdgcn_s_setprio(1);
#pragma unroll
            for (int kvh = 0; kvh < 2; ++kvh) {
                bf16x8 pf = *(const bf16x8*)(mypw + ((kvh * 64 + g * 16) ^ swzl));
#pragma unroll
                for (int dt = 0; dt < 4; ++dt) {
                    const int rv = dt * 16 + l16;
                    bf16x8 vf = *(const bf16x8*)(sV[cur] + rv * 128 + (((kvh * 4 + g) << 4) ^ swzl));
                    accO[dt] = mfma16(vf, pf, accO[dt]);
                }
            }
            __builtin_amdgcn_s_setprio(0);
            __syncthreads();                     // bar2: drains vmcnt (K/V staged)
        }
        // final per-q-row reduce of lsum partials across the 4 kv-groups
        float v = lsum;
        v += __shfl_xor(v, 16);
        v += __shfl_xor(v, 32);
        float inv = 1.f / v;
        // O^T: lane owns col q=l16; row d = dt*16 + g*4 + r -> ctx bf16 [4096][1024]
        unsigned short* cp = ctx + (size_t)(b * 2048 + wq0 + l16) * 1024 + h * 64 + g * 4;
#pragma unroll
        for (int dt = 0; dt < 4; ++dt) {
            u32x2 o;
            o[0] = cvt_pk_bf16(accO[dt][0] * inv, accO[dt][1] * inv);
            o[1] = cvt_pk_bf16(accO[dt][2] * inv, accO[dt][3] * inv);
            *(u32x2*)(cp + dt * 16) = o;
        }
    }
}

// ---------------------------------------------------------------------------
extern "C" void kernel_launch(void* const* d_in, const int* in_sizes, int n_in,
                              void* d_out, int out_size, void* d_ws, size_t ws_size,
                              hipStream_t stream) {
    const float* query = (const float*)d_in[0];
    const float* key   = (const float*)d_in[1];
    const float* value = (const float*)d_in[2];
    // d_in[3] = mask: fixed causal tril, applied analytically
    const float* wq = (const float*)d_in[4];
    const float* bq = (const float*)d_in[5];
    const float* wk = (const float*)d_in[6];
    const float* bk = (const float*)d_in[7];
    const float* wv = (const float*)d_in[8];
    const float* bv = (const float*)d_in[9];
    const float* wo = (const float*)d_in[10];
    const float* bo = (const float*)d_in[11];
    float* out = (float*)d_out;

    char* ws = (char*)d_ws;
    unsigned short* Wtq = (unsigned short*)ws;                 // 4 x 2MB: 0..8MB
    unsigned short* Wtk = Wtq + 1024 * 1024;
    unsigned short* Wtv = Wtk + 1024 * 1024;
    unsigned short* Wto = Wtv + 1024 * 1024;
    unsigned short* Q2  = Wto + 1024 * 1024;                   // 8..16MB
    unsigned short* K2  = Q2 + 4096 * 1024;                    // 16..24MB
    unsigned short* Vt  = K2 + 4096 * 1024;                    // 24..32MB (V written transposed)
    unsigned short* Aq  = Vt + 4096 * 1024;                    // 32..40MB (bf16 activations)
    unsigned short* Ak  = Aq + 4096 * 1024;                    // 40..48MB
    unsigned short* Av  = Ak + 4096 * 1024;                    // 48..56MB
    // Aq/Ak dead after k_gemm_qkv -> reuse Ak for ctx:
    unsigned short* ctx = Ak;                                  // 40..48MB

    dim3 blk(256);
    k_prep<<<dim3(7168), blk, 0, stream>>>(wq, wk, wv, wo, query, key, value,
                                           Wtq, Wtk, Wtv, Wto, Aq, Ak, Av);

    k_gemm_qkv<<<dim3(64, 8, 3), blk, 49152, stream>>>(Aq, Ak, Av,
                                                       Wtq, Wtk, Wtv, bq, bk, bv,
                                                       Q2, K2, Vt);

    k_attn<<<dim3(1024), dim3(128), 0, stream>>>(Q2, K2, Vt, ctx);

    k_gemm_o<<<dim3(64, 8), blk, 49152, stream>>>(ctx, Wto, bo, out);
}